// Round 8
// baseline (240.287 us; speedup 1.0000x reference)
//
#include <hip/hip_runtime.h>

// Causal GQA prefill attention, flash-style, bf16 MFMA / fp32 softmax.
// B=2, S=2048, H=32, HKV=8, D=128, G=4.
// Prepass 1: K fp32 -> Kbf bf16 [b][hkv][S][D]      (d_ws +0,   8 MB)
// Prepass 2: V fp32 -> Vt  bf16 [b][hkv][D][S]      (d_ws +8MB, 8 MB)
// Round 6: XCD remap cut FETCH 157->42 MB but time flat: kernel is
//   latency-bound on the per-iteration chain (~4450 cyc/iter vs ~1500
//   pipe demand). Counted-vmcnt / setprio / sched_barrier: no help.
// Round 7 (this): KVBLK=64 as TWO proven 32-wide sub-tiles (all LDS
//   swizzles byte-identical to round 5). One __syncthreads per 64-k
//   iteration -> 34 barrier-iterations per block instead of 66; 2x
//   work per iter fills the latency pole. Dropped setprio/raw-barrier/
//   sched_barrier (m190/m141: hurt lockstep blocks). LDS 74.7 KB ->
//   2 blocks/CU at launch_bounds(256,2).

#define B_   2
#define S_   2048
#define H_   32
#define HKV_ 8
#define D_   128
#define SCALEF 0.08838834764831845f
#define COEF  (SCALEF * 1.44269504088896340736f)   // scale * log2(e)
#define DEFER_THR 8.0f                             // log2-domain defer-max

typedef float          f32x4 __attribute__((ext_vector_type(4)));
typedef __bf16         bf16x4 __attribute__((ext_vector_type(4)));
typedef __bf16         bf16x8 __attribute__((ext_vector_type(8)));
typedef unsigned short u16x8 __attribute__((ext_vector_type(8)));

#define MFMA16(a, b, c) __builtin_amdgcn_mfma_f32_16x16x32_bf16((a), (b), (c), 0, 0, 0)

#if defined(__has_builtin)
#if __has_builtin(__builtin_amdgcn_exp2f)
#define EXP2F(x) __builtin_amdgcn_exp2f(x)
#endif
#endif
#ifndef EXP2F
#define EXP2F(x) exp2f(x)
#endif

static __device__ __forceinline__ unsigned short f2bf(float f) {
  unsigned int u = __builtin_bit_cast(unsigned int, f);
  u = (u + 0x7fffu + ((u >> 16) & 1u)) >> 16;   // RNE; inputs finite
  return (unsigned short)u;
}

// async global->LDS, 16B per lane; lds dest = wave-uniform base + lane*16.
static __device__ __forceinline__ void load_lds16(const void* g, void* l) {
  __builtin_amdgcn_global_load_lds(
      (const __attribute__((address_space(1))) void*)g,
      (__attribute__((address_space(3))) void*)l, 16, 0, 0);
}

// lane^16 exchange (DS pipe, within 32-lane halves): BitMode xor=16.
static __device__ __forceinline__ float swz_x16(float v) {
  return __builtin_bit_cast(
      float, __builtin_amdgcn_ds_swizzle(__builtin_bit_cast(int, v), 0x401F));
}
// generic pull from lane (byteaddr/4): full 64-lane crossbar.
static __device__ __forceinline__ float bperm_f(int byteaddr, float v) {
  return __builtin_bit_cast(
      float,
      __builtin_amdgcn_ds_bpermute(byteaddr, __builtin_bit_cast(int, v)));
}

// ------------- Prepass 1: K fp32 -> bf16 [b][hkv][S][D] -------------
__global__ __launch_bounds__(256) void k_convert_kernel(
    const float* __restrict__ k, unsigned short* __restrict__ kbf) {
  int t = blockIdx.x * 256 + threadIdx.x;
  int o = t * 8;                       // output-linear index
  int d = o & (D_ - 1);
  int s = (o >> 7) & (S_ - 1);
  int bh = o >> 18;                    // 0..15
  int b = bh >> 3, hkv = bh & 7;
  const float* src = k + (size_t)(b * S_ + s) * (HKV_ * D_) + hkv * D_ + d;
  f32x4 x0 = *(const f32x4*)src;
  f32x4 x1 = *(const f32x4*)(src + 4);
  u16x8 w;
  w[0] = f2bf(x0[0]); w[1] = f2bf(x0[1]); w[2] = f2bf(x0[2]); w[3] = f2bf(x0[3]);
  w[4] = f2bf(x1[0]); w[5] = f2bf(x1[1]); w[6] = f2bf(x1[2]); w[7] = f2bf(x1[3]);
  *(u16x8*)(kbf + o) = w;
}

// ------------- Prepass 2: V -> Vt (bf16, [b][hkv][D][S]) -------------
__global__ __launch_bounds__(256) void vt_transpose_kernel(
    const float* __restrict__ v, unsigned short* __restrict__ vt) {
  __shared__ float tile[32][65];  // +1 pad: conflict-free
  const int tid = threadIdx.x;
  const int s0 = blockIdx.x * 64;   // 32 s-tiles
  const int d0 = blockIdx.y * 32;   // 4 d-tiles
  const int bh = blockIdx.z;        // 16 (b*8+hkv)
  const float* src = v + (size_t)(bh >> 3) * S_ * (HKV_ * D_) + (bh & 7) * D_;
#pragma unroll
  for (int it = 0; it < 8; ++it) {
    int idx = it * 256 + tid;
    int sl = idx >> 5, dl = idx & 31;  // coalesced along d
    tile[dl][sl] = src[(size_t)(s0 + sl) * (HKV_ * D_) + d0 + dl];
  }
  __syncthreads();
  unsigned int* dst = (unsigned int*)vt;
#pragma unroll
  for (int it = 0; it < 4; ++it) {
    int idx = it * 256 + tid;
    int dl = idx >> 5, sp = idx & 31;
    unsigned int w = (unsigned int)f2bf(tile[dl][2 * sp]) |
                     ((unsigned int)f2bf(tile[dl][2 * sp + 1]) << 16);
    dst[(((size_t)bh * D_ + d0 + dl) * S_ + s0 + 2 * sp) >> 1] = w;
  }
}

// ------------- Main attention kernel -------------
#define PSTR 72  // PL row stride in shorts (144 B: 16B-aligned, 2-way banks)

__global__ __launch_bounds__(256, 2) void attn_kernel(
    const float* __restrict__ qg, const unsigned short* __restrict__ kbfg,
    const unsigned short* __restrict__ vtg, float* __restrict__ outg) {
  // KVBLK=64 as two 32-wide sub-tiles with the round-5-proven layouts.
  __shared__ unsigned short KL[2][2][32 * 128];   // 2dbuf x 2sub x 8 KB
  __shared__ unsigned short VL[2][2][128 * 32];   // 2dbuf x 2sub x 8 KB
  __shared__ unsigned short PL[4][16 * PSTR];     // 4 x 2.25 KB (per-wave P)

  const int tid = threadIdx.x;
  const int wave = tid >> 6, lane = tid & 63;
  const int l15 = lane & 15, quad = lane >> 4;
  const int a32 = ((lane ^ 32) << 2);  // bpermute addr: lane+-32 partner
  const int rowa = quad << 4;          // bpermute addr base: row quad*4

  // XCD-locality remap: dispatch id round-robins xcd = id&7 (8 XCDs).
  const int id = (int)blockIdx.x + 16 * (int)blockIdx.y;  // 0..1023
  const int xcd = id & 7, slot = id >> 3;                 // slot 0..127
  const int bhkv = xcd * 2 + (slot >> 6);
  const int inner = slot & 63;
  const int g = inner >> 4;         // 0..3 head-in-group
  const int xb = inner & 15;        // causal pair index
  const int b = bhkv >> 3, hkv = bhkv & 7;
  const int h = hkv * 4 + g;

  const unsigned short* kbf = kbfg + (size_t)(b * HKV_ + hkv) * S_ * D_;
  const unsigned short* vtb = vtg + (size_t)(b * HKV_ + hkv) * D_ * S_;

  const f32x4 zero4 = {0.f, 0.f, 0.f, 0.f};
  const float NEG_INF = -__builtin_huge_valf();

  // ---- async staging of one 64-wide K/Vt tile (2 sub-tiles) ----
  // K chunk swizzle (per sub): phys chunk pc of row kr holds pc^(kr&15).
  // V chunk swizzle (per sub): phys chunk pc of row dr holds pc^((dr>>1)&3).
  auto stage = [&](int kt, int buf) {
#pragma unroll
    for (int sub = 0; sub < 2; ++sub)
#pragma unroll
      for (int j = 0; j < 2; ++j) {
        int si = wave * 128 + j * 64 + lane;
        int kr = si >> 4, pc = si & 15;
        int lc = pc ^ (kr & 15);
        load_lds16(kbf + (size_t)(kt * 64 + sub * 32 + kr) * D_ + lc * 8,
                   &KL[buf][sub][(wave * 128 + j * 64) * 8]);
      }
#pragma unroll
    for (int sub = 0; sub < 2; ++sub)
#pragma unroll
      for (int j = 0; j < 2; ++j) {
        int si = wave * 128 + j * 64 + lane;
        int dr = si >> 2, pc = si & 3;
        int lc = pc ^ ((dr >> 1) & 3);
        load_lds16(vtb + (size_t)dr * S_ + kt * 64 + sub * 32 + lc * 8,
                   &VL[buf][sub][(wave * 128 + j * 64) * 8]);
      }
  };

  for (int ph = 0; ph < 2; ++ph) {
    const int qb = ph ? (31 - xb) : xb;
    const int qbase = qb * 64 + wave * 16;  // this wave's 16 q rows
    const int qgp = qbase + l15;            // this lane's q-row (swapped C)

    // Q fragments (A/B-layout identical), pre-scaled by COEF.
    bf16x8 qf[4];
#pragma unroll
    for (int ch = 0; ch < 4; ++ch) {
      const float* p = qg + (size_t)(b * S_ + qbase + l15) * (H_ * D_) +
                       h * D_ + ch * 32 + quad * 8;
      f32x4 x0 = *(const f32x4*)p;
      f32x4 x1 = *(const f32x4*)(p + 4);
      bf16x8 t;
      t[0] = (__bf16)(x0[0] * COEF); t[1] = (__bf16)(x0[1] * COEF);
      t[2] = (__bf16)(x0[2] * COEF); t[3] = (__bf16)(x0[3] * COEF);
      t[4] = (__bf16)(x1[0] * COEF); t[5] = (__bf16)(x1[1] * COEF);
      t[6] = (__bf16)(x1[2] * COEF); t[7] = (__bf16)(x1[3] * COEF);
      qf[ch] = t;
    }

    f32x4 acc[8];
#pragma unroll
    for (int dt = 0; dt < 8; ++dt) acc[dt] = zero4;
    float mrow = NEG_INF;  // running max of row q=l15 (scalar)
    float lsum = 0.f;      // lane-partial sum of row q=l15 over own k-cols

    const int nkt = qb + 1;  // 64-wide k-tiles

    stage(0, 0);
    __syncthreads();  // drains vmcnt: tile 0 resident

    for (int kt = 0; kt < nkt; ++kt) {
      const int cur = kt & 1;
      if (kt + 1 < nkt) stage(kt + 1, cur ^ 1);  // async, lands under compute

      if (kt * 64 <= qbase + 15) {  // wave-uniform: skip fully-masked tiles
        // ---- QK^T (swapped): sc[h2][r] = S[k=kb0+h2*16+quad*4+r][q=l15]
        f32x4 sc[4] = {zero4, zero4, zero4, zero4};
#pragma unroll
        for (int h2 = 0; h2 < 4; ++h2) {
          const unsigned short* KS =
              &KL[cur][h2 >> 1][((h2 & 1) * 16 + l15) * D_];
#pragma unroll
          for (int ch = 0; ch < 4; ++ch) {
            const int pc = (ch * 4 + quad) ^ l15;  // un-swizzle
            u16x8 kf = *(const u16x8*)&KS[pc * 8];
            sc[h2] = MFMA16(__builtin_bit_cast(bf16x8, kf), qf[ch], sc[h2]);
          }
        }
        const int kb0 = kt * 64;
        // causal mask (boundary sub-tiles only)
#pragma unroll
        for (int h2 = 0; h2 < 4; ++h2) {
          if (kb0 + h2 * 16 + 15 > qbase) {
            int kb2 = kb0 + h2 * 16 + quad * 4;
#pragma unroll
            for (int r = 0; r < 4; ++r) {
              if (kb2 + r > qgp) sc[h2][r] = NEG_INF;
            }
          }
        }
        // ---- defer-max (T13): lane's 16 scores are all row q=l15 ----
        float l8 = NEG_INF;
#pragma unroll
        for (int h2 = 0; h2 < 4; ++h2)
          l8 = fmaxf(l8, fmaxf(fmaxf(sc[h2][0], sc[h2][1]),
                               fmaxf(sc[h2][2], sc[h2][3])));
        if (!__all(l8 <= mrow + DEFER_THR)) {
          float t = fmaxf(l8, swz_x16(l8));  // cross-quad row max
          t = fmaxf(t, bperm_f(a32, t));
          float mn = fmaxf(mrow, t);
          float al = EXP2F(mrow - mn);
          mrow = mn;
          lsum *= al;
          f32x4 av;  // alpha for acc rows quad*4+r, from lanes r' = row
#pragma unroll
          for (int r = 0; r < 4; ++r) av[r] = bperm_f(rowa + (r << 2), al);
#pragma unroll
          for (int dt = 0; dt < 8; ++dt)
#pragma unroll
            for (int r = 0; r < 4; ++r) acc[dt][r] *= av[r];
        }
        // ---- shared P computation (P bounded by 2^THR = 256) ----
#pragma unroll
        for (int h2 = 0; h2 < 4; ++h2)
#pragma unroll
          for (int r = 0; r < 4; ++r) sc[h2][r] = EXP2F(sc[h2][r] - mrow);
#pragma unroll
        for (int h2 = 0; h2 < 4; ++h2)
          lsum += (sc[h2][0] + sc[h2][1]) + (sc[h2][2] + sc[h2][3]);
        // P -> PL row q=l15, cols h2*16+quad*4+{0..3}: 4x ds_write_b64
#pragma unroll
        for (int h2 = 0; h2 < 4; ++h2) {
          bf16x4 w;
          w[0] = (__bf16)sc[h2][0]; w[1] = (__bf16)sc[h2][1];
          w[2] = (__bf16)sc[h2][2]; w[3] = (__bf16)sc[h2][3];
          *(bf16x4*)&PL[wave][l15 * PSTR + h2 * 16 + quad * 4] = w;
        }
        // ---- PV: two K=32 halves; A = P rows q=l15, B = Vt sub kh ----
#pragma unroll
        for (int kh = 0; kh < 2; ++kh) {
          u16x8 pf = *(const u16x8*)&PL[wave][l15 * PSTR + kh * 32 + quad * 8];
          bf16x8 pb = __builtin_bit_cast(bf16x8, pf);
          const int vsw = (quad ^ ((l15 >> 1) & 3)) * 8;  // un-swizzle V
#pragma unroll
          for (int dt = 0; dt < 8; ++dt) {
            u16x8 vf =
                *(const u16x8*)&VL[cur][kh][(dt * 16 + l15) * 32 + vsw];
            acc[dt] = MFMA16(pb, __builtin_bit_cast(bf16x8, vf), acc[dt]);
          }
        }
      }
      __syncthreads();  // drains vmcnt (next tile resident) + publishes bufs
    }

    // ---- epilogue: row sum via butterfly, redistribute inv to acc rows ----
    float s = lsum;
    s += swz_x16(s);
    s += bperm_f(a32, s);
    float linv = 1.0f / s;  // valid at every lane for row q=l15
    f32x4 inv;
#pragma unroll
    for (int r = 0; r < 4; ++r) inv[r] = bperm_f(rowa + (r << 2), linv);
#pragma unroll
    for (int dt = 0; dt < 8; ++dt)
#pragma unroll
      for (int r = 0; r < 4; ++r)
        outg[(size_t)(b * S_ + qbase + quad * 4 + r) * (H_ * D_) +
             h * D_ + dt * 16 + l15] = acc[dt][r] * inv[r];
  }
}

extern "C" void kernel_launch(void* const* d_in, const int* in_sizes, int n_in,
                              void* d_out, int out_size, void* d_ws,
                              size_t ws_size, hipStream_t stream) {
  const float* q = (const float*)d_in[0];
  const float* k = (const float*)d_in[1];
  const float* v = (const float*)d_in[2];
  float* out = (float*)d_out;
  unsigned short* kws = (unsigned short*)d_ws;               // 8 MB Kbf
  unsigned short* vtws = kws + (size_t)B_ * HKV_ * S_ * D_;  // 8 MB Vt

  k_convert_kernel<<<(B_ * S_ * HKV_ * D_ / 8) / 256, 256, 0, stream>>>(k, kws);

  dim3 g1(S_ / 64, D_ / 32, B_ * HKV_);
  vt_transpose_kernel<<<g1, 256, 0, stream>>>(v, vtws);

  dim3 g2(16, B_ * H_);  // 1024 blocks; XCD-locality remap inside kernel
  attn_kernel<<<g2, 256, 0, stream>>>(q, kws, vtws, out);
}